// Round 9
// baseline (2537.999 us; speedup 1.0000x reference)
//
#include <hip/hip_runtime.h>

#define S_LEN 2048
#define DMODEL 256
#define DINNER 512
#define NCHUNK 64
#define CLEN 32

typedef unsigned short u16;
typedef short bf16x8 __attribute__((ext_vector_type(8)));
typedef unsigned short u16x8 __attribute__((ext_vector_type(8)));  // 16 bytes
typedef float f32x4 __attribute__((ext_vector_type(4)));

__device__ __forceinline__ float bf2f(u16 u) {
  unsigned int x = ((unsigned int)u) << 16;
  float f; __builtin_memcpy(&f, &x, 4); return f;
}
__device__ __forceinline__ u16 f2bf(float f) {
  unsigned int x; __builtin_memcpy(&x, &f, 4);
  return (u16)((x + 0x7FFFu + ((x >> 16) & 1u)) >> 16);
}
__device__ __forceinline__ float ldw(const void* p, size_t i, int isbf) {
  return isbf ? bf2f(((const u16*)p)[i]) : ((const float*)p)[i];
}
__device__ __forceinline__ float siluf(float x) { return x / (1.f + __expf(-x)); }
__device__ __forceinline__ float softplusf(float x) {
  if (x > 20.f) return x;
  return log1pf(__expf(x));
}

// Detect input dtype (bf16 vs f32) from exponent-byte statistics.
__global__ __launch_bounds__(256) void detect_kernel(const void* __restrict__ x,
                                                     int* __restrict__ flag) {
  __shared__ int cnt;
  if (threadIdx.x == 0) cnt = 0;
  __syncthreads();
  u16 u = ((const u16*)x)[2 * threadIdx.x];
  int e = (u >> 7) & 0xFF;
  if (e >= 0x60 && e <= 0x8F) atomicAdd(&cnt, 1);
  __syncthreads();
  if (threadIdx.x == 0) *flag = (cnt > 128) ? 1 : 0;
}

// ---------------- weight pre-pack into MFMA fragment order ----------------
// Packed W[K][N]: chunk c = n_blk16*(K/32) + k_blk32, 512 bf16 per chunk;
// inside: q*128 + (n&15)*8 + (k&7). B-frag read = contiguous ds_read_b128.
__global__ __launch_bounds__(256) void wpack_kernel(
    const void* __restrict__ src, const int* __restrict__ pf,
    u16* __restrict__ dst, int K, int N)
{
  const int isbf = *pf;
  __shared__ float tile[32][65];
  int nb64 = blockIdx.x, kb = blockIdx.y, mat = blockIdx.z;
  size_t so = (size_t)mat * K * N;
  int tid = threadIdx.x;
  int kk = tid >> 3, nseg = (tid & 7) * 8;
#pragma unroll
  for (int j = 0; j < 8; ++j)
    tile[kk][nseg + j] = ldw(src, so + (size_t)(kb * 32 + kk) * N + nb64 * 64 + nseg + j, isbf);
  __syncthreads();
  int cc = tid >> 6, i0 = (tid & 63) * 8;
  int q = i0 >> 7, nn = (i0 >> 3) & 15;
  u16 outv[8];
#pragma unroll
  for (int j = 0; j < 8; ++j) outv[j] = f2bf(tile[q * 8 + j][cc * 16 + nn]);
  size_t doff = (size_t)mat * K * N + ((size_t)(nb64 * 4 + cc) * (K >> 5) + kb) * 512 + i0;
  *(u16x8*)(dst + doff) = *(const u16x8*)outv;
}

// Fused xd_w|xB_w|xC_w -> packed [4][512][64] (K=512, N=64).
__global__ __launch_bounds__(256) void wpack_fused_kernel(
    const void* __restrict__ xdw, const void* __restrict__ xBw, const void* __restrict__ xCw,
    const int* __restrict__ pf, u16* __restrict__ dst)
{
  const int isbf = *pf;
  __shared__ float tile[32][65];
  int kb = blockIdx.y, mat = blockIdx.z;
  int tid = threadIdx.x;
  int kk = tid >> 3, nseg = (tid & 7) * 8;
  int k = kb * 32 + kk;
#pragma unroll
  for (int j = 0; j < 8; ++j) {
    int n = nseg + j; float v;
    if (n < 32)      v = ldw(xdw, (size_t)mat * 16384 + (size_t)k * 32 + n, isbf);
    else if (n < 48) v = ldw(xBw, (size_t)mat * 8192 + (size_t)k * 16 + (n - 32), isbf);
    else             v = ldw(xCw, (size_t)mat * 8192 + (size_t)k * 16 + (n - 48), isbf);
    tile[kk][n] = v;
  }
  __syncthreads();
  int cc = tid >> 6, i0 = (tid & 63) * 8;
  int q = i0 >> 7, nn = (i0 >> 3) & 15;
  u16 outv[8];
#pragma unroll
  for (int j = 0; j < 8; ++j) outv[j] = f2bf(tile[q * 8 + j][cc * 16 + nn]);
  size_t doff = (size_t)mat * 512 * 64 + ((size_t)cc * 16 + kb) * 512 + i0;
  *(u16x8*)(dst + doff) = *(const u16x8*)outv;
}

// ---------------- LayerNorm: residual f32 + bf16 normalized out ----------------
__global__ __launch_bounds__(256) void ln_kernel(
    const void* __restrict__ src, int src_is_ext, int rev,
    const void* __restrict__ g, const void* __restrict__ bta, size_t wo,
    const int* __restrict__ pf, float* __restrict__ res, u16* __restrict__ xnb)
{
  const int isbf = *pf;
  int r = blockIdx.x;
  int tid = threadIdx.x;
  int b = r >> 11, s = r & 2047;
  int sr = rev ? (b * S_LEN + (S_LEN - 1 - s)) : r;
  float v;
  if (src_is_ext) v = ldw(src, (size_t)sr * DMODEL + tid, isbf);
  else            v = ((const float*)src)[(size_t)sr * DMODEL + tid];
  res[(size_t)r * DMODEL + tid] = v;
  float s1 = v, s2 = v * v;
#pragma unroll
  for (int o = 32; o > 0; o >>= 1) {
    s1 += __shfl_xor(s1, o, 64);
    s2 += __shfl_xor(s2, o, 64);
  }
  __shared__ float r1[4], r2[4];
  if ((tid & 63) == 0) { r1[tid >> 6] = s1; r2[tid >> 6] = s2; }
  __syncthreads();
  s1 = r1[0] + r1[1] + r1[2] + r1[3];
  s2 = r2[0] + r2[1] + r2[2] + r2[3];
  float mean = s1 * (1.f / DMODEL);
  float var  = s2 * (1.f / DMODEL) - mean * mean;
  float inv  = rsqrtf(var + 1e-5f);
  xnb[(size_t)r * DMODEL + tid] =
      f2bf((v - mean) * inv * ldw(g, wo + tid, isbf) + ldw(bta, wo + tid, isbf));
}

// ---------------- MFMA GEMM: C[M,N] = A(bf16 row-major) @ Wp(packed) [+res] ----------
// BM=128, BK=32, 256 thr = 4 waves. BN=128: waves 2x2 (64x64 each). BN=64: 4x1.
// OUTMODE 0: f32. 1: final dtype per flag. 2: bf16.
// OUTMODE 3: bf16 into cat buffer (row stride 512), optional row reversal + col offset.
template<int BN, int OUTMODE>
__global__ __launch_bounds__(256) void mfma_gemm(
    const u16* __restrict__ A, const u16* __restrict__ Wp, size_t wo,
    const float* __restrict__ res, void* __restrict__ Out,
    const int* __restrict__ pf, int N, int K, int rev, int coff)
{
  const int isbf = *pf;
  __shared__ __align__(16) u16 Asb[128 * 32];
  __shared__ __align__(16) u16 Bsb[BN * 32];
  int tid = threadIdx.x;
  int n0 = blockIdx.x * BN, m0 = blockIdx.y * 128;
  int w = tid >> 6, lane = tid & 63;
  int q = lane >> 4, r = lane & 15;
  constexpr int WM = (BN == 128) ? 4 : 2;
  const int wm0 = (BN == 128) ? ((w >> 1) * 4) : (w * 2);
  const int wn0 = (BN == 128) ? ((w & 1) * 4) : 0;
  f32x4 acc[WM][4];
#pragma unroll
  for (int i = 0; i < WM; ++i)
#pragma unroll
    for (int j = 0; j < 4; ++j) acc[i][j] = (f32x4){0.f, 0.f, 0.f, 0.f};

  const int kbs = K >> 5;
  int sm = tid >> 1, sq = (tid & 1) * 2;
  const u16* arow = A + (size_t)(m0 + sm) * K + sq * 8;
  u16* adst0 = Asb + ((sm >> 4) * 4 + sq) * 128 + (sm & 15) * 8;
  u16* adst1 = Asb + ((sm >> 4) * 4 + sq + 1) * 128 + (sm & 15) * 8;

  for (int k0 = 0; k0 < K; k0 += 32) {
    u16x8 a0 = *(const u16x8*)(arow + k0);
    u16x8 a1 = *(const u16x8*)(arow + k0 + 8);
    *(u16x8*)adst0 = a0;
    *(u16x8*)adst1 = a1;
#pragma unroll
    for (int p = tid; p < BN * 4; p += 256) {
      int nb = p >> 6, inner = (p & 63) * 8;
      const u16* srcb = Wp + wo + ((size_t)((n0 >> 4) + nb) * kbs + (k0 >> 5)) * 512 + inner;
      *(u16x8*)(Bsb + nb * 512 + inner) = *(const u16x8*)srcb;
    }
    __syncthreads();
    bf16x8 af[WM], bfr[4];
#pragma unroll
    for (int i = 0; i < WM; ++i)
      af[i] = *(const bf16x8*)(Asb + ((wm0 + i) * 4 + q) * 128 + r * 8);
#pragma unroll
    for (int j = 0; j < 4; ++j)
      bfr[j] = *(const bf16x8*)(Bsb + ((wn0 + j) * 4 + q) * 128 + r * 8);
#pragma unroll
    for (int i = 0; i < WM; ++i)
#pragma unroll
      for (int j = 0; j < 4; ++j)
        acc[i][j] = __builtin_amdgcn_mfma_f32_16x16x32_bf16(af[i], bfr[j], acc[i][j], 0, 0, 0);
    __syncthreads();
  }
#pragma unroll
  for (int i = 0; i < WM; ++i) {
    int rowb = m0 + (wm0 + i) * 16 + q * 4;
#pragma unroll
    for (int j = 0; j < 4; ++j) {
      int col = n0 + (wn0 + j) * 16 + r;
#pragma unroll
      for (int t = 0; t < 4; ++t) {
        int row = rowb + t;
        float v = acc[i][j][t];
        size_t lidx = (size_t)row * N + col;
        if (res) v += res[lidx];
        if (OUTMODE == 0)      ((float*)Out)[lidx] = v;
        else if (OUTMODE == 2) ((u16*)Out)[lidx] = f2bf(v);
        else if (OUTMODE == 3) {
          int bb = row >> 11, ss = row & 2047;
          int orow = rev ? (bb * S_LEN + (S_LEN - 1 - ss)) : row;
          ((u16*)Out)[(size_t)orow * 512 + col + coff] = f2bf(v);
        } else {
          if (isbf) ((u16*)Out)[lidx] = f2bf(v); else ((float*)Out)[lidx] = v;
        }
      }
    }
  }
}

// ---------------- causal depthwise conv K=4 + bias + SiLU (bf16 in/out) -------------
__global__ __launch_bounds__(256) void conv_kernel(
    const u16* __restrict__ xzb, const void* __restrict__ cw, const void* __restrict__ cb,
    size_t ow, size_t ob, const int* __restrict__ pf, u16* __restrict__ xcb)
{
  const int isbf = *pf;
  int idx = blockIdx.x * 256 + threadIdx.x;  // 4096*512
  int r = idx >> 9, d = idx & 511;
  int b = r >> 11, s = r & 2047;
  float acc = ldw(cb, ob + d, isbf);
#pragma unroll
  for (int k = 0; k < 4; ++k) {
    int t = s - 3 + k;
    if (t >= 0)
      acc += ldw(cw, ow + (size_t)d * 4 + k, isbf) * bf2f(xzb[((size_t)(b * S_LEN + t) << 10) + d]);
  }
  xcb[idx] = f2bf(siluf(acc));
}

// ---------------- One-pass SSM scan ----------------
// Grid (32 d-chunks, 2 b), 256 threads = 16 d x 16 n. Each block walks all 64
// chunks sequentially; h carried in registers; double-buffered LDS staging with
// register prefetch of chunk c+1; delta computed in-kernel; gated bf16 output.
__global__ __launch_bounds__(256) void scan_full_kernel(
    const u16* __restrict__ xcb, const float* __restrict__ dBC,
    const u16* __restrict__ xzb,
    const void* __restrict__ A_log, size_t oA,
    const void* __restrict__ Dp, size_t oD,
    const void* __restrict__ dtpw, size_t owt,
    const void* __restrict__ dtpb, size_t obt,
    const int* __restrict__ pf, u16* __restrict__ ymb)
{
  const int isbf = *pf;
  __shared__ float sall[2][32][65];  // dBC rows: [0:32)=dt, [32:48)=B, [48:64)=C
  __shared__ float sx[2][32][17];
  __shared__ float sz[2][32][17];
  __shared__ float sw[32][17];
  __shared__ float sd[32][17];
  __shared__ float sy[32][17];
  __shared__ float sbias[16];
  int tid = threadIdx.x;
  int n = tid & 15, dl = tid >> 4;
  int d0 = blockIdx.x << 4;
  int b = blockIdx.y;
  int base = b * S_LEN;

  for (int l = tid; l < 512; l += 256) {
    int j = l >> 4, e = l & 15;
    sw[j][e] = ldw(dtpw, owt + (size_t)j * 512 + d0 + e, isbf);
  }
  if (tid < 16) sbias[tid] = ldw(dtpb, obt + d0 + tid, isbf);
  float Ac = -__expf(ldw(A_log, oA + (size_t)(d0 + dl) * 16 + n, isbf));
  float Dv = ldw(Dp, oD + d0 + dl, isbf);

  // staging roles: all threads -> 8 dBC floats; wave0 -> sx, wave1 -> sz.
  int arow = tid >> 3, acol = (tid & 7) * 8;
  int xrow = (tid & 63) >> 1, xcol = (tid & 1) * 8;

  {  // stage chunk 0
    const float* p = dBC + (size_t)(base + arow) * 64 + acol;
    float4 v0 = *(const float4*)p, v1 = *(const float4*)(p + 4);
    sall[0][arow][acol + 0] = v0.x; sall[0][arow][acol + 1] = v0.y;
    sall[0][arow][acol + 2] = v0.z; sall[0][arow][acol + 3] = v0.w;
    sall[0][arow][acol + 4] = v1.x; sall[0][arow][acol + 5] = v1.y;
    sall[0][arow][acol + 6] = v1.z; sall[0][arow][acol + 7] = v1.w;
    if (tid < 64) {
      u16x8 xv = *(const u16x8*)(xcb + (size_t)(base + xrow) * 512 + d0 + xcol);
#pragma unroll
      for (int k = 0; k < 8; ++k) sx[0][xrow][xcol + k] = bf2f(xv[k]);
    } else if (tid < 128) {
      u16x8 zv = *(const u16x8*)(xzb + ((size_t)(base + xrow) << 10) + 512 + d0 + xcol);
#pragma unroll
      for (int k = 0; k < 8; ++k) sz[0][xrow][xcol + k] = bf2f(zv[k]);
    }
  }
  __syncthreads();

  float h = 0.f;
  for (int c = 0; c < NCHUNK; ++c) {
    int nb = c & 1;
    int row0 = base + c * CLEN;
    // prefetch chunk c+1 into registers
    float4 pv0 = {}, pv1 = {}; u16x8 pxz = {};
    const bool have = (c + 1 < NCHUNK);
    if (have) {
      const float* p = dBC + (size_t)(row0 + CLEN + arow) * 64 + acol;
      pv0 = *(const float4*)p; pv1 = *(const float4*)(p + 4);
      if (tid < 64)
        pxz = *(const u16x8*)(xcb + (size_t)(row0 + CLEN + xrow) * 512 + d0 + xcol);
      else if (tid < 128)
        pxz = *(const u16x8*)(xzb + ((size_t)(row0 + CLEN + xrow) << 10) + 512 + d0 + xcol);
    }
    // delta = softplus(dt-part @ dtp_w + bias)
    for (int l = tid; l < 512; l += 256) {
      int rr = l >> 4, e = l & 15;
      float a = sbias[e];
#pragma unroll 8
      for (int j = 0; j < 32; ++j) a += sall[nb][rr][j] * sw[j][e];
      sd[rr][e] = softplusf(a);
    }
    __syncthreads();
    // recurrence steps
#pragma unroll 8
    for (int tt = 0; tt < CLEN; ++tt) {
      float de = sd[tt][dl];
      float xv = sx[nb][tt][dl];
      float bv = sall[nb][tt][32 + n];
      float cv = sall[nb][tt][48 + n];
      h = __expf(de * Ac) * h + de * xv * bv;
      float yc = h * cv;
      yc += __shfl_xor(yc, 1, 64);
      yc += __shfl_xor(yc, 2, 64);
      yc += __shfl_xor(yc, 4, 64);
      yc += __shfl_xor(yc, 8, 64);
      if (n == 0) sy[tt][dl] = yc + Dv * xv;
    }
    __syncthreads();
    // gated write
    for (int l = tid; l < 512; l += 256) {
      int rr = l >> 4, e = l & 15;
      ymb[(size_t)(row0 + rr) * 512 + d0 + e] = f2bf(sy[rr][e] * siluf(sz[nb][rr][e]));
    }
    // commit prefetched chunk to the other buffer
    if (have) {
      int ob = 1 - nb;
      sall[ob][arow][acol + 0] = pv0.x; sall[ob][arow][acol + 1] = pv0.y;
      sall[ob][arow][acol + 2] = pv0.z; sall[ob][arow][acol + 3] = pv0.w;
      sall[ob][arow][acol + 4] = pv1.x; sall[ob][arow][acol + 5] = pv1.y;
      sall[ob][arow][acol + 6] = pv1.z; sall[ob][arow][acol + 7] = pv1.w;
      if (tid < 64) {
#pragma unroll
        for (int k = 0; k < 8; ++k) sx[ob][xrow][xcol + k] = bf2f(pxz[k]);
      } else if (tid < 128) {
#pragma unroll
        for (int k = 0; k < 8; ++k) sz[ob][xrow][xcol + k] = bf2f(pxz[k]);
      }
    }
    __syncthreads();
  }
}

extern "C" void kernel_launch(void* const* d_in, const int* in_sizes, int n_in,
                              void* d_out, int out_size, void* d_ws, size_t ws_size,
                              hipStream_t stream)
{
  const void* x       = d_in[0];
  const void* in_w    = d_in[1];
  const void* conv_w  = d_in[2];
  const void* conv_b  = d_in[3];
  const void* A_log   = d_in[4];
  const void* xd_w    = d_in[5];
  const void* xB_w    = d_in[6];
  const void* xC_w    = d_in[7];
  const void* dtp_w   = d_in[8];
  const void* dtp_b   = d_in[9];
  const void* Dp      = d_in[10];
  const void* out_w   = d_in[11];
  const void* ln_g    = d_in[12];
  const void* ln_b    = d_in[13];
  const void* merge_w = d_in[14];

  const size_t M = 4096;
  // ---- workspace (~35 MB; proven-safe >= 50.5 MB) ----
  float* ws    = (float*)d_ws;
  float* res   = ws;                                        // 1.00 M floats
  float* dBC   = res + M * 256;                             // 0.25 M
  float* obA   = dBC + M * 64;                              // 1.00 M (blocks 0,2)
  u16*   xn_bf = (u16*)(obA + M * 256);                     // 1 M u16
  u16*   xz_bf = xn_bf + M * 256;                           // 4 M u16
  u16*   xc_bf = xz_bf + M * 1024;                          // 2 M u16
  u16*   ym_bf = xc_bf + M * 512;                           // 2 M u16
  u16*   cat_bf= ym_bf + M * 512;                           // 2 M u16
  u16*   Wp_in = cat_bf + M * 512;                          // 1 M u16
  u16*   Wp_out= Wp_in + (size_t)4 * 256 * 1024;            // 0.5 M u16
  u16*   Wp_mg = Wp_out + (size_t)4 * 512 * 256;            // 128 K u16
  u16*   Wp_all= Wp_mg + (size_t)512 * 256;                 // 128 K u16
  int*   flagp = (int*)(Wp_all + (size_t)4 * 512 * 64);

  dim3 blk(256);
  hipLaunchKernelGGL(detect_kernel, dim3(1), blk, 0, stream, x, flagp);
  hipLaunchKernelGGL(wpack_kernel, dim3(16, 8, 4), blk, 0, stream, in_w, flagp, Wp_in, 256, 1024);
  hipLaunchKernelGGL(wpack_kernel, dim3(4, 16, 4), blk, 0, stream, out_w, flagp, Wp_out, 512, 256);
  hipLaunchKernelGGL(wpack_kernel, dim3(4, 16, 1), blk, 0, stream, merge_w, flagp, Wp_mg, 512, 256);
  hipLaunchKernelGGL(wpack_fused_kernel, dim3(1, 16, 4), blk, 0, stream,
      xd_w, xB_w, xC_w, flagp, Wp_all);

  for (int i = 0; i < 4; ++i) {
    const void* src; int ext, rev;
    if (i == 0)      { src = x;   ext = 1; rev = 0; }
    else if (i == 1) { src = obA; ext = 0; rev = 0; }
    else if (i == 2) { src = x;   ext = 1; rev = 1; }
    else             { src = obA; ext = 0; rev = 0; }

    hipLaunchKernelGGL(ln_kernel, dim3(4096), blk, 0, stream,
        src, ext, rev, ln_g, ln_b, (size_t)i * 256, flagp, res, xn_bf);
    hipLaunchKernelGGL((mfma_gemm<128, 2>), dim3(8, 32), blk, 0, stream,
        xn_bf, Wp_in, (size_t)i * 256 * 1024, (const float*)nullptr, (void*)xz_bf,
        flagp, 1024, 256, 0, 0);
    hipLaunchKernelGGL(conv_kernel, dim3(8192), blk, 0, stream,
        xz_bf, conv_w, conv_b, (size_t)i * 512 * 4, (size_t)i * 512, flagp, xc_bf);
    hipLaunchKernelGGL((mfma_gemm<64, 0>), dim3(1, 32), blk, 0, stream,
        xc_bf, Wp_all, (size_t)i * 512 * 64, (const float*)nullptr, (void*)dBC,
        flagp, 64, 512, 0, 0);
    hipLaunchKernelGGL(scan_full_kernel, dim3(32, 2), blk, 0, stream,
        xc_bf, dBC, xz_bf, A_log, (size_t)i * 512 * 16, Dp, (size_t)i * 512,
        dtp_w, (size_t)i * 32 * 512, dtp_b, (size_t)i * 512,
        flagp, ym_bf);
    if (i == 0 || i == 2) {
      hipLaunchKernelGGL((mfma_gemm<128, 0>), dim3(2, 32), blk, 0, stream,
          ym_bf, Wp_out, (size_t)i * 512 * 256, res, (void*)obA, flagp, 256, 512, 0, 0);
    } else {
      hipLaunchKernelGGL((mfma_gemm<128, 3>), dim3(2, 32), blk, 0, stream,
          ym_bf, Wp_out, (size_t)i * 512 * 256, res, (void*)cat_bf, flagp, 256, 512,
          (i == 3) ? 1 : 0, (i == 1) ? 0 : 256);
    }
  }
  hipLaunchKernelGGL((mfma_gemm<128, 1>), dim3(2, 32), blk, 0, stream,
      cat_bf, Wp_mg, (size_t)0, (const float*)nullptr, d_out, flagp, 256, 512, 0, 0);
}

// Round 10
// 1346.519 us; speedup vs baseline: 1.8849x; 1.8849x over previous
//
#include <hip/hip_runtime.h>

#define S_LEN 2048
#define DMODEL 256
#define DINNER 512
#define NCHUNK 64
#define CLEN 32

typedef unsigned short u16;
typedef short bf16x8 __attribute__((ext_vector_type(8)));
typedef unsigned short u16x8 __attribute__((ext_vector_type(8)));  // 16 bytes
typedef float f32x4 __attribute__((ext_vector_type(4)));

__device__ __forceinline__ float bf2f(u16 u) {
  unsigned int x = ((unsigned int)u) << 16;
  float f; __builtin_memcpy(&f, &x, 4); return f;
}
__device__ __forceinline__ u16 f2bf(float f) {
  unsigned int x; __builtin_memcpy(&x, &f, 4);
  return (u16)((x + 0x7FFFu + ((x >> 16) & 1u)) >> 16);
}
__device__ __forceinline__ float ldw(const void* p, size_t i, int isbf) {
  return isbf ? bf2f(((const u16*)p)[i]) : ((const float*)p)[i];
}
__device__ __forceinline__ float siluf(float x) { return x / (1.f + __expf(-x)); }
__device__ __forceinline__ float softplusf(float x) {
  if (x > 20.f) return x;
  return log1pf(__expf(x));
}

// Detect input dtype (bf16 vs f32) from exponent-byte statistics.
__global__ __launch_bounds__(256) void detect_kernel(const void* __restrict__ x,
                                                     int* __restrict__ flag) {
  __shared__ int cnt;
  if (threadIdx.x == 0) cnt = 0;
  __syncthreads();
  u16 u = ((const u16*)x)[2 * threadIdx.x];
  int e = (u >> 7) & 0xFF;
  if (e >= 0x60 && e <= 0x8F) atomicAdd(&cnt, 1);
  __syncthreads();
  if (threadIdx.x == 0) *flag = (cnt > 128) ? 1 : 0;
}

// ---------------- weight pre-pack into MFMA fragment order ----------------
__global__ __launch_bounds__(256) void wpack_kernel(
    const void* __restrict__ src, const int* __restrict__ pf,
    u16* __restrict__ dst, int K, int N)
{
  const int isbf = *pf;
  __shared__ float tile[32][65];
  int nb64 = blockIdx.x, kb = blockIdx.y, mat = blockIdx.z;
  size_t so = (size_t)mat * K * N;
  int tid = threadIdx.x;
  int kk = tid >> 3, nseg = (tid & 7) * 8;
#pragma unroll
  for (int j = 0; j < 8; ++j)
    tile[kk][nseg + j] = ldw(src, so + (size_t)(kb * 32 + kk) * N + nb64 * 64 + nseg + j, isbf);
  __syncthreads();
  int cc = tid >> 6, i0 = (tid & 63) * 8;
  int q = i0 >> 7, nn = (i0 >> 3) & 15;
  u16 outv[8];
#pragma unroll
  for (int j = 0; j < 8; ++j) outv[j] = f2bf(tile[q * 8 + j][cc * 16 + nn]);
  size_t doff = (size_t)mat * K * N + ((size_t)(nb64 * 4 + cc) * (K >> 5) + kb) * 512 + i0;
  *(u16x8*)(dst + doff) = *(const u16x8*)outv;
}

// Fused xd_w|xB_w|xC_w -> packed [4][512][64] (K=512, N=64).
__global__ __launch_bounds__(256) void wpack_fused_kernel(
    const void* __restrict__ xdw, const void* __restrict__ xBw, const void* __restrict__ xCw,
    const int* __restrict__ pf, u16* __restrict__ dst)
{
  const int isbf = *pf;
  __shared__ float tile[32][65];
  int kb = blockIdx.y, mat = blockIdx.z;
  int tid = threadIdx.x;
  int kk = tid >> 3, nseg = (tid & 7) * 8;
  int k = kb * 32 + kk;
#pragma unroll
  for (int j = 0; j < 8; ++j) {
    int n = nseg + j; float v;
    if (n < 32)      v = ldw(xdw, (size_t)mat * 16384 + (size_t)k * 32 + n, isbf);
    else if (n < 48) v = ldw(xBw, (size_t)mat * 8192 + (size_t)k * 16 + (n - 32), isbf);
    else             v = ldw(xCw, (size_t)mat * 8192 + (size_t)k * 16 + (n - 48), isbf);
    tile[kk][n] = v;
  }
  __syncthreads();
  int cc = tid >> 6, i0 = (tid & 63) * 8;
  int q = i0 >> 7, nn = (i0 >> 3) & 15;
  u16 outv[8];
#pragma unroll
  for (int j = 0; j < 8; ++j) outv[j] = f2bf(tile[q * 8 + j][cc * 16 + nn]);
  size_t doff = (size_t)mat * 512 * 64 + ((size_t)cc * 16 + kb) * 512 + i0;
  *(u16x8*)(dst + doff) = *(const u16x8*)outv;
}

// ---------------- LayerNorm: residual f32 + bf16 normalized out ----------------
__global__ __launch_bounds__(256) void ln_kernel(
    const void* __restrict__ src, int src_is_ext, int rev,
    const void* __restrict__ g, const void* __restrict__ bta, size_t wo,
    const int* __restrict__ pf, float* __restrict__ res, u16* __restrict__ xnb)
{
  const int isbf = *pf;
  int r = blockIdx.x;
  int tid = threadIdx.x;
  int b = r >> 11, s = r & 2047;
  int sr = rev ? (b * S_LEN + (S_LEN - 1 - s)) : r;
  float v;
  if (src_is_ext) v = ldw(src, (size_t)sr * DMODEL + tid, isbf);
  else            v = ((const float*)src)[(size_t)sr * DMODEL + tid];
  res[(size_t)r * DMODEL + tid] = v;
  float s1 = v, s2 = v * v;
#pragma unroll
  for (int o = 32; o > 0; o >>= 1) {
    s1 += __shfl_xor(s1, o, 64);
    s2 += __shfl_xor(s2, o, 64);
  }
  __shared__ float r1[4], r2[4];
  if ((tid & 63) == 0) { r1[tid >> 6] = s1; r2[tid >> 6] = s2; }
  __syncthreads();
  s1 = r1[0] + r1[1] + r1[2] + r1[3];
  s2 = r2[0] + r2[1] + r2[2] + r2[3];
  float mean = s1 * (1.f / DMODEL);
  float var  = s2 * (1.f / DMODEL) - mean * mean;
  float inv  = rsqrtf(var + 1e-5f);
  xnb[(size_t)r * DMODEL + tid] =
      f2bf((v - mean) * inv * ldw(g, wo + tid, isbf) + ldw(bta, wo + tid, isbf));
}

// ---------------- MFMA GEMM: C[M,N] = A(bf16 row-major) @ Wp(packed) [+res] ----------
template<int BN, int OUTMODE>
__global__ __launch_bounds__(256) void mfma_gemm(
    const u16* __restrict__ A, const u16* __restrict__ Wp, size_t wo,
    const float* __restrict__ res, void* __restrict__ Out,
    const int* __restrict__ pf, int N, int K, int rev, int coff)
{
  const int isbf = *pf;
  __shared__ __align__(16) u16 Asb[128 * 32];
  __shared__ __align__(16) u16 Bsb[BN * 32];
  int tid = threadIdx.x;
  int n0 = blockIdx.x * BN, m0 = blockIdx.y * 128;
  int w = tid >> 6, lane = tid & 63;
  int q = lane >> 4, r = lane & 15;
  constexpr int WM = (BN == 128) ? 4 : 2;
  const int wm0 = (BN == 128) ? ((w >> 1) * 4) : (w * 2);
  const int wn0 = (BN == 128) ? ((w & 1) * 4) : 0;
  f32x4 acc[WM][4];
#pragma unroll
  for (int i = 0; i < WM; ++i)
#pragma unroll
    for (int j = 0; j < 4; ++j) acc[i][j] = (f32x4){0.f, 0.f, 0.f, 0.f};

  const int kbs = K >> 5;
  int sm = tid >> 1, sq = (tid & 1) * 2;
  const u16* arow = A + (size_t)(m0 + sm) * K + sq * 8;
  u16* adst0 = Asb + ((sm >> 4) * 4 + sq) * 128 + (sm & 15) * 8;
  u16* adst1 = Asb + ((sm >> 4) * 4 + sq + 1) * 128 + (sm & 15) * 8;

  for (int k0 = 0; k0 < K; k0 += 32) {
    u16x8 a0 = *(const u16x8*)(arow + k0);
    u16x8 a1 = *(const u16x8*)(arow + k0 + 8);
    *(u16x8*)adst0 = a0;
    *(u16x8*)adst1 = a1;
#pragma unroll
    for (int p = tid; p < BN * 4; p += 256) {
      int nb = p >> 6, inner = (p & 63) * 8;
      const u16* srcb = Wp + wo + ((size_t)((n0 >> 4) + nb) * kbs + (k0 >> 5)) * 512 + inner;
      *(u16x8*)(Bsb + nb * 512 + inner) = *(const u16x8*)srcb;
    }
    __syncthreads();
    bf16x8 af[WM], bfr[4];
#pragma unroll
    for (int i = 0; i < WM; ++i)
      af[i] = *(const bf16x8*)(Asb + ((wm0 + i) * 4 + q) * 128 + r * 8);
#pragma unroll
    for (int j = 0; j < 4; ++j)
      bfr[j] = *(const bf16x8*)(Bsb + ((wn0 + j) * 4 + q) * 128 + r * 8);
#pragma unroll
    for (int i = 0; i < WM; ++i)
#pragma unroll
      for (int j = 0; j < 4; ++j)
        acc[i][j] = __builtin_amdgcn_mfma_f32_16x16x32_bf16(af[i], bfr[j], acc[i][j], 0, 0, 0);
    __syncthreads();
  }
#pragma unroll
  for (int i = 0; i < WM; ++i) {
    int rowb = m0 + (wm0 + i) * 16 + q * 4;
#pragma unroll
    for (int j = 0; j < 4; ++j) {
      int col = n0 + (wn0 + j) * 16 + r;
#pragma unroll
      for (int t = 0; t < 4; ++t) {
        int row = rowb + t;
        float v = acc[i][j][t];
        size_t lidx = (size_t)row * N + col;
        if (res) v += res[lidx];
        if (OUTMODE == 0)      ((float*)Out)[lidx] = v;
        else if (OUTMODE == 2) ((u16*)Out)[lidx] = f2bf(v);
        else if (OUTMODE == 3) {
          int bb = row >> 11, ss = row & 2047;
          int orow = rev ? (bb * S_LEN + (S_LEN - 1 - ss)) : row;
          ((u16*)Out)[(size_t)orow * 512 + col + coff] = f2bf(v);
        } else {
          if (isbf) ((u16*)Out)[lidx] = f2bf(v); else ((float*)Out)[lidx] = v;
        }
      }
    }
  }
}

// ---------------- causal depthwise conv K=4 + bias + SiLU (bf16 in/out) -------------
__global__ __launch_bounds__(256) void conv_kernel(
    const u16* __restrict__ xzb, const void* __restrict__ cw, const void* __restrict__ cb,
    size_t ow, size_t ob, const int* __restrict__ pf, u16* __restrict__ xcb)
{
  const int isbf = *pf;
  int idx = blockIdx.x * 256 + threadIdx.x;  // 4096*512
  int r = idx >> 9, d = idx & 511;
  int b = r >> 11, s = r & 2047;
  float acc = ldw(cb, ob + d, isbf);
#pragma unroll
  for (int k = 0; k < 4; ++k) {
    int t = s - 3 + k;
    if (t >= 0)
      acc += ldw(cw, ow + (size_t)d * 4 + k, isbf) * bf2f(xzb[((size_t)(b * S_LEN + t) << 10) + d]);
  }
  xcb[idx] = f2bf(siluf(acc));
}

// ---------------- 3-phase scan, thread-per-d, n-states in registers ----------------
// Phase 1: per-chunk aggregates. Grid (2 dblk, NCHUNK, B). Thread owns d = d0+tid,
// carries 16 (h, prodA) pairs in registers; delta from 32 in-register weights.
__global__ __launch_bounds__(256) void scan_p1_kernel(
    const u16* __restrict__ xcb, const float* __restrict__ dBC,
    const void* __restrict__ A_log, size_t oA,
    const void* __restrict__ dtpw, size_t owt, const void* __restrict__ dtpb, size_t obt,
    const int* __restrict__ pf, float* __restrict__ aggA, float* __restrict__ aggB)
{
  const int isbf = *pf;
  __shared__ float sall[32][64];   // dBC rows: [0:32)=dt, [32:48)=B, [48:64)=C
  __shared__ u16 sxu[32][256];
  int tid = threadIdx.x;
  int d0 = blockIdx.x << 8;
  int c = blockIdx.y, b = blockIdx.z;
  int row0 = b * S_LEN + c * CLEN;
  int d = d0 + tid;
  {
    int t = tid >> 3, e0 = (tid & 7) * 8;
    const float* p = dBC + (size_t)(row0 + t) * 64 + e0;
    *(f32x4*)&sall[t][e0]     = *(const f32x4*)p;
    *(f32x4*)&sall[t][e0 + 4] = *(const f32x4*)(p + 4);
  }
#pragma unroll
  for (int k = 0; k < 2; ++k) {
    int v = k * 256 + tid;
    int t = v >> 5, s = (v & 31) * 8;
    *(u16x8*)&sxu[t][s] = *(const u16x8*)(xcb + (size_t)(row0 + t) * 512 + d0 + s);
  }
  float w_[32];
#pragma unroll
  for (int j = 0; j < 32; ++j) w_[j] = ldw(dtpw, owt + (size_t)j * 512 + d, isbf);
  float bias = ldw(dtpb, obt + d, isbf);
  __syncthreads();
  float del[32];
#pragma unroll
  for (int t = 0; t < 32; ++t) {
    float a = bias;
#pragma unroll
    for (int j4 = 0; j4 < 8; ++j4) {
      f32x4 v = *(const f32x4*)&sall[t][j4 * 4];
      a += v[0] * w_[j4 * 4] + v[1] * w_[j4 * 4 + 1] + v[2] * w_[j4 * 4 + 2] + v[3] * w_[j4 * 4 + 3];
    }
    del[t] = softplusf(a);
  }
  float Ac[16];
#pragma unroll
  for (int n = 0; n < 16; ++n) Ac[n] = -__expf(ldw(A_log, oA + (size_t)d * 16 + n, isbf));
  float h[16], ap[16];
#pragma unroll
  for (int n = 0; n < 16; ++n) { h[n] = 0.f; ap[n] = 1.f; }
#pragma unroll
  for (int t = 0; t < 32; ++t) {
    float de = del[t];
    float dx = de * bf2f(sxu[t][tid]);
    f32x4 B0 = *(const f32x4*)&sall[t][32];
    f32x4 B1 = *(const f32x4*)&sall[t][36];
    f32x4 B2 = *(const f32x4*)&sall[t][40];
    f32x4 B3 = *(const f32x4*)&sall[t][44];
#pragma unroll
    for (int n = 0; n < 16; ++n) {
      float bv = (n < 4) ? B0[n] : (n < 8) ? B1[n - 4] : (n < 12) ? B2[n - 8] : B3[n - 12];
      float e = __expf(de * Ac[n]);
      h[n] = e * h[n] + dx * bv;
      ap[n] *= e;
    }
  }
  size_t o = (((size_t)(b * NCHUNK + c) * DINNER) + d) * 16;
#pragma unroll
  for (int k = 0; k < 4; ++k) {
    f32x4 va = {ap[k * 4], ap[k * 4 + 1], ap[k * 4 + 2], ap[k * 4 + 3]};
    f32x4 vb = {h[k * 4], h[k * 4 + 1], h[k * 4 + 2], h[k * 4 + 3]};
    *(f32x4*)(aggA + o + k * 4) = va;
    *(f32x4*)(aggB + o + k * 4) = vb;
  }
}

// Phase 2: exclusive prefix over chunks in place (aggB -> hpref).
__global__ __launch_bounds__(256) void scan_prefix_kernel(
    const float* __restrict__ aggA, float* __restrict__ aggB)
{
  int idx = blockIdx.x * 256 + threadIdx.x;
  int n = idx & 15, d = (idx >> 4) & 511, b = idx >> 13;
  float h = 0.f;
  for (int c = 0; c < NCHUNK; ++c) {
    size_t o = (((size_t)(b * NCHUNK + c) * DINNER) + d) * 16 + n;
    float a = aggA[o], t = aggB[o];
    aggB[o] = h;
    h = a * h + t;
  }
}

// Phase 3: replay with true initial state; register C-contraction; gated bf16 out.
__global__ __launch_bounds__(256) void scan_p3_kernel(
    const u16* __restrict__ xcb, const float* __restrict__ dBC,
    const u16* __restrict__ xzb, const float* __restrict__ hpref,
    const void* __restrict__ A_log, size_t oA, const void* __restrict__ Dp, size_t oD,
    const void* __restrict__ dtpw, size_t owt, const void* __restrict__ dtpb, size_t obt,
    const int* __restrict__ pf, u16* __restrict__ ymb)
{
  const int isbf = *pf;
  __shared__ float sall[32][64];
  __shared__ u16 sxu[32][256];
  __shared__ u16 szu[32][256];
  int tid = threadIdx.x;
  int d0 = blockIdx.x << 8;
  int c = blockIdx.y, b = blockIdx.z;
  int row0 = b * S_LEN + c * CLEN;
  int d = d0 + tid;
  {
    int t = tid >> 3, e0 = (tid & 7) * 8;
    const float* p = dBC + (size_t)(row0 + t) * 64 + e0;
    *(f32x4*)&sall[t][e0]     = *(const f32x4*)p;
    *(f32x4*)&sall[t][e0 + 4] = *(const f32x4*)(p + 4);
  }
#pragma unroll
  for (int k = 0; k < 2; ++k) {
    int v = k * 256 + tid;
    int t = v >> 5, s = (v & 31) * 8;
    *(u16x8*)&sxu[t][s] = *(const u16x8*)(xcb + (size_t)(row0 + t) * 512 + d0 + s);
    *(u16x8*)&szu[t][s] = *(const u16x8*)(xzb + ((size_t)(row0 + t) << 10) + 512 + d0 + s);
  }
  float w_[32];
#pragma unroll
  for (int j = 0; j < 32; ++j) w_[j] = ldw(dtpw, owt + (size_t)j * 512 + d, isbf);
  float bias = ldw(dtpb, obt + d, isbf);
  __syncthreads();
  float del[32];
#pragma unroll
  for (int t = 0; t < 32; ++t) {
    float a = bias;
#pragma unroll
    for (int j4 = 0; j4 < 8; ++j4) {
      f32x4 v = *(const f32x4*)&sall[t][j4 * 4];
      a += v[0] * w_[j4 * 4] + v[1] * w_[j4 * 4 + 1] + v[2] * w_[j4 * 4 + 2] + v[3] * w_[j4 * 4 + 3];
    }
    del[t] = softplusf(a);
  }
  float Ac[16];
#pragma unroll
  for (int n = 0; n < 16; ++n) Ac[n] = -__expf(ldw(A_log, oA + (size_t)d * 16 + n, isbf));
  float Dv = ldw(Dp, oD + d, isbf);
  float h[16];
  size_t o = (((size_t)(b * NCHUNK + c) * DINNER) + d) * 16;
#pragma unroll
  for (int k = 0; k < 4; ++k) {
    f32x4 v = *(const f32x4*)(hpref + o + k * 4);
    h[k * 4] = v[0]; h[k * 4 + 1] = v[1]; h[k * 4 + 2] = v[2]; h[k * 4 + 3] = v[3];
  }
#pragma unroll
  for (int t = 0; t < 32; ++t) {
    float de = del[t];
    float xv = bf2f(sxu[t][tid]);
    float dx = de * xv;
    f32x4 B0 = *(const f32x4*)&sall[t][32];
    f32x4 B1 = *(const f32x4*)&sall[t][36];
    f32x4 B2 = *(const f32x4*)&sall[t][40];
    f32x4 B3 = *(const f32x4*)&sall[t][44];
    f32x4 C0 = *(const f32x4*)&sall[t][48];
    f32x4 C1 = *(const f32x4*)&sall[t][52];
    f32x4 C2 = *(const f32x4*)&sall[t][56];
    f32x4 C3 = *(const f32x4*)&sall[t][60];
    float yc0 = 0.f, yc1 = 0.f, yc2 = 0.f, yc3 = 0.f;
#pragma unroll
    for (int n = 0; n < 16; ++n) {
      float bv = (n < 4) ? B0[n] : (n < 8) ? B1[n - 4] : (n < 12) ? B2[n - 8] : B3[n - 12];
      float cv = (n < 4) ? C0[n] : (n < 8) ? C1[n - 4] : (n < 12) ? C2[n - 8] : C3[n - 12];
      float e = __expf(de * Ac[n]);
      h[n] = e * h[n] + dx * bv;
      if ((n & 3) == 0)      yc0 += h[n] * cv;
      else if ((n & 3) == 1) yc1 += h[n] * cv;
      else if ((n & 3) == 2) yc2 += h[n] * cv;
      else                   yc3 += h[n] * cv;
    }
    float y = (yc0 + yc1) + (yc2 + yc3) + Dv * xv;
    float z = bf2f(szu[t][tid]);
    ymb[(size_t)(row0 + t) * 512 + d] = f2bf(y * siluf(z));
  }
}

extern "C" void kernel_launch(void* const* d_in, const int* in_sizes, int n_in,
                              void* d_out, int out_size, void* d_ws, size_t ws_size,
                              hipStream_t stream)
{
  const void* x       = d_in[0];
  const void* in_w    = d_in[1];
  const void* conv_w  = d_in[2];
  const void* conv_b  = d_in[3];
  const void* A_log   = d_in[4];
  const void* xd_w    = d_in[5];
  const void* xB_w    = d_in[6];
  const void* xC_w    = d_in[7];
  const void* dtp_w   = d_in[8];
  const void* dtp_b   = d_in[9];
  const void* Dp      = d_in[10];
  const void* out_w   = d_in[11];
  const void* ln_g    = d_in[12];
  const void* ln_b    = d_in[13];
  const void* merge_w = d_in[14];

  const size_t M = 4096;
  // ---- workspace (~43 MB; proven-safe >= 50.5 MB) ----
  float* ws    = (float*)d_ws;
  float* res   = ws;                                        // 1.00 M floats
  float* dBC   = res + M * 256;                             // 0.25 M
  float* aggA  = dBC + M * 64;                              // 1.00 M
  float* aggB  = aggA + (size_t)2 * NCHUNK * DINNER * 16;   // 1.00 M (-> hpref)
  float* obA   = aggB + (size_t)2 * NCHUNK * DINNER * 16;   // 1.00 M (blocks 0,2)
  u16*   xn_bf = (u16*)(obA + M * 256);                     // 1 M u16
  u16*   xz_bf = xn_bf + M * 256;                           // 4 M u16
  u16*   xc_bf = xz_bf + M * 1024;                          // 2 M u16
  u16*   ym_bf = xc_bf + M * 512;                           // 2 M u16
  u16*   cat_bf= ym_bf + M * 512;                           // 2 M u16
  u16*   Wp_in = cat_bf + M * 512;                          // 1 M u16
  u16*   Wp_out= Wp_in + (size_t)4 * 256 * 1024;            // 0.5 M u16
  u16*   Wp_mg = Wp_out + (size_t)4 * 512 * 256;            // 128 K u16
  u16*   Wp_all= Wp_mg + (size_t)512 * 256;                 // 128 K u16
  int*   flagp = (int*)(Wp_all + (size_t)4 * 512 * 64);

  dim3 blk(256);
  hipLaunchKernelGGL(detect_kernel, dim3(1), blk, 0, stream, x, flagp);
  hipLaunchKernelGGL(wpack_kernel, dim3(16, 8, 4), blk, 0, stream, in_w, flagp, Wp_in, 256, 1024);
  hipLaunchKernelGGL(wpack_kernel, dim3(4, 16, 4), blk, 0, stream, out_w, flagp, Wp_out, 512, 256);
  hipLaunchKernelGGL(wpack_kernel, dim3(4, 16, 1), blk, 0, stream, merge_w, flagp, Wp_mg, 512, 256);
  hipLaunchKernelGGL(wpack_fused_kernel, dim3(1, 16, 4), blk, 0, stream,
      xd_w, xB_w, xC_w, flagp, Wp_all);

  for (int i = 0; i < 4; ++i) {
    const void* src; int ext, rev;
    if (i == 0)      { src = x;   ext = 1; rev = 0; }
    else if (i == 1) { src = obA; ext = 0; rev = 0; }
    else if (i == 2) { src = x;   ext = 1; rev = 1; }
    else             { src = obA; ext = 0; rev = 0; }

    hipLaunchKernelGGL(ln_kernel, dim3(4096), blk, 0, stream,
        src, ext, rev, ln_g, ln_b, (size_t)i * 256, flagp, res, xn_bf);
    hipLaunchKernelGGL((mfma_gemm<128, 2>), dim3(8, 32), blk, 0, stream,
        xn_bf, Wp_in, (size_t)i * 256 * 1024, (const float*)nullptr, (void*)xz_bf,
        flagp, 1024, 256, 0, 0);
    hipLaunchKernelGGL(conv_kernel, dim3(8192), blk, 0, stream,
        xz_bf, conv_w, conv_b, (size_t)i * 512 * 4, (size_t)i * 512, flagp, xc_bf);
    hipLaunchKernelGGL((mfma_gemm<64, 0>), dim3(1, 32), blk, 0, stream,
        xc_bf, Wp_all, (size_t)i * 512 * 64, (const float*)nullptr, (void*)dBC,
        flagp, 64, 512, 0, 0);
    hipLaunchKernelGGL(scan_p1_kernel, dim3(2, NCHUNK, 2), blk, 0, stream,
        xc_bf, dBC, A_log, (size_t)i * 512 * 16,
        dtp_w, (size_t)i * 32 * 512, dtp_b, (size_t)i * 512,
        flagp, aggA, aggB);
    hipLaunchKernelGGL(scan_prefix_kernel, dim3(64), blk, 0, stream, aggA, aggB);
    hipLaunchKernelGGL(scan_p3_kernel, dim3(2, NCHUNK, 2), blk, 0, stream,
        xc_bf, dBC, xz_bf, aggB, A_log, (size_t)i * 512 * 16, Dp, (size_t)i * 512,
        dtp_w, (size_t)i * 32 * 512, dtp_b, (size_t)i * 512,
        flagp, ym_bf);
    if (i == 0 || i == 2) {
      hipLaunchKernelGGL((mfma_gemm<128, 0>), dim3(2, 32), blk, 0, stream,
          ym_bf, Wp_out, (size_t)i * 512 * 256, res, (void*)obA, flagp, 256, 512, 0, 0);
    } else {
      hipLaunchKernelGGL((mfma_gemm<128, 3>), dim3(2, 32), blk, 0, stream,
          ym_bf, Wp_out, (size_t)i * 512 * 256, res, (void*)cat_bf, flagp, 256, 512,
          (i == 3) ? 1 : 0, (i == 1) ? 0 : 256);
    }
  }
  hipLaunchKernelGGL((mfma_gemm<128, 1>), dim3(2, 32), blk, 0, stream,
      cat_bf, Wp_mg, (size_t)0, (const float*)nullptr, d_out, flagp, 256, 512, 0, 0);
}

// Round 11
// 487.439 us; speedup vs baseline: 5.2068x; 2.7624x over previous
//
#include <hip/hip_runtime.h>

#define S_LEN 2048
#define DINNER 512
#define NCHUNK 64
#define CLEN 32

typedef unsigned short u16;
typedef short bf16x8 __attribute__((ext_vector_type(8)));
typedef unsigned short u16x8 __attribute__((ext_vector_type(8)));  // 16 bytes
typedef float f32x4 __attribute__((ext_vector_type(4)));

__device__ __forceinline__ float bf2f(u16 u) {
  unsigned int x = ((unsigned int)u) << 16;
  float f; __builtin_memcpy(&f, &x, 4); return f;
}
__device__ __forceinline__ u16 f2bf(float f) {
  unsigned int x; __builtin_memcpy(&x, &f, 4);
  return (u16)((x + 0x7FFFu + ((x >> 16) & 1u)) >> 16);
}
__device__ __forceinline__ float ldw(const void* p, size_t i, int isbf) {
  return isbf ? bf2f(((const u16*)p)[i]) : ((const float*)p)[i];
}
__device__ __forceinline__ float siluf(float x) { return x / (1.f + __expf(-x)); }
__device__ __forceinline__ float softplusf(float x) {
  if (x > 20.f) return x;
  return log1pf(__expf(x));
}

// Detect input dtype (bf16 vs f32) from exponent-byte statistics.
__global__ __launch_bounds__(256) void detect_kernel(const void* __restrict__ x,
                                                     int* __restrict__ flag) {
  __shared__ int cnt;
  if (threadIdx.x == 0) cnt = 0;
  __syncthreads();
  u16 u = ((const u16*)x)[2 * threadIdx.x];
  int e = (u >> 7) & 0xFF;
  if (e >= 0x60 && e <= 0x8F) atomicAdd(&cnt, 1);
  __syncthreads();
  if (threadIdx.x == 0) *flag = (cnt > 128) ? 1 : 0;
}

// ---------------- weight pre-pack into MFMA fragment order ----------------
__global__ __launch_bounds__(256) void wpack_kernel(
    const void* __restrict__ src, const int* __restrict__ pf,
    u16* __restrict__ dst, int K, int N)
{
  const int isbf = *pf;
  __shared__ float tile[32][65];
  int nb64 = blockIdx.x, kb = blockIdx.y, mat = blockIdx.z;
  size_t so = (size_t)mat * K * N;
  int tid = threadIdx.x;
  int kk = tid >> 3, nseg = (tid & 7) * 8;
#pragma unroll
  for (int j = 0; j < 8; ++j)
    tile[kk][nseg + j] = ldw(src, so + (size_t)(kb * 32 + kk) * N + nb64 * 64 + nseg + j, isbf);
  __syncthreads();
  int cc = tid >> 6, i0 = (tid & 63) * 8;
  int q = i0 >> 7, nn = (i0 >> 3) & 15;
  u16 outv[8];
#pragma unroll
  for (int j = 0; j < 8; ++j) outv[j] = f2bf(tile[q * 8 + j][cc * 16 + nn]);
  size_t doff = (size_t)mat * K * N + ((size_t)(nb64 * 4 + cc) * (K >> 5) + kb) * 512 + i0;
  *(u16x8*)(dst + doff) = *(const u16x8*)outv;
}

// Fused xd_w|xB_w|xC_w -> packed [4][512][64] (K=512, N=64).
__global__ __launch_bounds__(256) void wpack_fused_kernel(
    const void* __restrict__ xdw, const void* __restrict__ xBw, const void* __restrict__ xCw,
    const int* __restrict__ pf, u16* __restrict__ dst)
{
  const int isbf = *pf;
  __shared__ float tile[32][65];
  int kb = blockIdx.y, mat = blockIdx.z;
  int tid = threadIdx.x;
  int kk = tid >> 3, nseg = (tid & 7) * 8;
  int k = kb * 32 + kk;
#pragma unroll
  for (int j = 0; j < 8; ++j) {
    int n = nseg + j; float v;
    if (n < 32)      v = ldw(xdw, (size_t)mat * 16384 + (size_t)k * 32 + n, isbf);
    else if (n < 48) v = ldw(xBw, (size_t)mat * 8192 + (size_t)k * 16 + (n - 32), isbf);
    else             v = ldw(xCw, (size_t)mat * 8192 + (size_t)k * 16 + (n - 48), isbf);
    tile[kk][n] = v;
  }
  __syncthreads();
  int cc = tid >> 6, i0 = (tid & 63) * 8;
  int q = i0 >> 7, nn = (i0 >> 3) & 15;
  u16 outv[8];
#pragma unroll
  for (int j = 0; j < 8; ++j) outv[j] = f2bf(tile[q * 8 + j][cc * 16 + nn]);
  size_t doff = (size_t)mat * 512 * 64 + ((size_t)cc * 16 + kb) * 512 + i0;
  *(u16x8*)(dst + doff) = *(const u16x8*)outv;
}

// ---------------- LayerNorm (batched 2 chains): residual f32 + bf16 out ----------------
// grid 8192 rows; rows 0-4095 = chain0, 4096-8191 = chain1 (time-reversed at input).
__global__ __launch_bounds__(256) void ln_kernel(
    const void* __restrict__ x, const u16* __restrict__ obA, int it,
    const void* __restrict__ g, const void* __restrict__ bta,
    const int* __restrict__ pf, float* __restrict__ res, u16* __restrict__ xnb)
{
  const int isbf = *pf;
  int r = blockIdx.x;
  int tid = threadIdx.x;
  int chain = r >> 12, rr = r & 4095;
  int i = chain * 2 + it;
  size_t wo = (size_t)i * 256;
  float v;
  if (it == 0) {
    int b = rr >> 11, s = rr & 2047;
    int sr = chain ? (b * S_LEN + (S_LEN - 1 - s)) : rr;
    v = ldw(x, (size_t)sr * 256 + tid, isbf);
  } else {
    v = bf2f(obA[(size_t)r * 256 + tid]);
  }
  res[(size_t)r * 256 + tid] = v;
  float s1 = v, s2 = v * v;
#pragma unroll
  for (int o = 32; o > 0; o >>= 1) {
    s1 += __shfl_xor(s1, o, 64);
    s2 += __shfl_xor(s2, o, 64);
  }
  __shared__ float r1[4], r2[4];
  if ((tid & 63) == 0) { r1[tid >> 6] = s1; r2[tid >> 6] = s2; }
  __syncthreads();
  s1 = r1[0] + r1[1] + r1[2] + r1[3];
  s2 = r2[0] + r2[1] + r2[2] + r2[3];
  float mean = s1 * (1.f / 256.f);
  float var  = s2 * (1.f / 256.f) - mean * mean;
  float inv  = rsqrtf(var + 1e-5f);
  xnb[(size_t)r * 256 + tid] =
      f2bf((v - mean) * inv * ldw(g, wo + tid, isbf) + ldw(bta, wo + tid, isbf));
}

// ---------------- MFMA GEMM, batched weights per row-half ----------------
// OUTMODE 0: f32. 1: final dtype per flag. 2: bf16. 3: cat buffer (stride 512,
// rows>=4096 un-reversed into cols 256-511).
template<int BN, int OUTMODE>
__global__ __launch_bounds__(256) void mfma_gemm(
    const u16* __restrict__ A, const u16* __restrict__ Wp, size_t woA, size_t woB, int mhalf,
    const float* __restrict__ res, void* __restrict__ Out,
    const int* __restrict__ pf, int N, int K)
{
  const int isbf = *pf;
  __shared__ __align__(16) u16 Asb[128 * 32];
  __shared__ __align__(16) u16 Bsb[BN * 32];
  int tid = threadIdx.x;
  int n0 = blockIdx.x * BN, m0 = blockIdx.y * 128;
  size_t wo = (mhalf && m0 >= mhalf) ? woB : woA;
  int w = tid >> 6, lane = tid & 63;
  int q = lane >> 4, r = lane & 15;
  constexpr int WM = (BN == 128) ? 4 : 2;
  const int wm0 = (BN == 128) ? ((w >> 1) * 4) : (w * 2);
  const int wn0 = (BN == 128) ? ((w & 1) * 4) : 0;
  f32x4 acc[WM][4];
#pragma unroll
  for (int i = 0; i < WM; ++i)
#pragma unroll
    for (int j = 0; j < 4; ++j) acc[i][j] = (f32x4){0.f, 0.f, 0.f, 0.f};

  const int kbs = K >> 5;
  int sm = tid >> 1, sq = (tid & 1) * 2;
  const u16* arow = A + (size_t)(m0 + sm) * K + sq * 8;
  u16* adst0 = Asb + ((sm >> 4) * 4 + sq) * 128 + (sm & 15) * 8;
  u16* adst1 = Asb + ((sm >> 4) * 4 + sq + 1) * 128 + (sm & 15) * 8;

  for (int k0 = 0; k0 < K; k0 += 32) {
    u16x8 a0 = *(const u16x8*)(arow + k0);
    u16x8 a1 = *(const u16x8*)(arow + k0 + 8);
    *(u16x8*)adst0 = a0;
    *(u16x8*)adst1 = a1;
#pragma unroll
    for (int p = tid; p < BN * 4; p += 256) {
      int nb = p >> 6, inner = (p & 63) * 8;
      const u16* srcb = Wp + wo + ((size_t)((n0 >> 4) + nb) * kbs + (k0 >> 5)) * 512 + inner;
      *(u16x8*)(Bsb + nb * 512 + inner) = *(const u16x8*)srcb;
    }
    __syncthreads();
    bf16x8 af[WM], bfr[4];
#pragma unroll
    for (int i = 0; i < WM; ++i)
      af[i] = *(const bf16x8*)(Asb + ((wm0 + i) * 4 + q) * 128 + r * 8);
#pragma unroll
    for (int j = 0; j < 4; ++j)
      bfr[j] = *(const bf16x8*)(Bsb + ((wn0 + j) * 4 + q) * 128 + r * 8);
#pragma unroll
    for (int i = 0; i < WM; ++i)
#pragma unroll
      for (int j = 0; j < 4; ++j)
        acc[i][j] = __builtin_amdgcn_mfma_f32_16x16x32_bf16(af[i], bfr[j], acc[i][j], 0, 0, 0);
    __syncthreads();
  }
#pragma unroll
  for (int i = 0; i < WM; ++i) {
    int rowb = m0 + (wm0 + i) * 16 + q * 4;
#pragma unroll
    for (int j = 0; j < 4; ++j) {
      int col = n0 + (wn0 + j) * 16 + r;
#pragma unroll
      for (int t = 0; t < 4; ++t) {
        int row = rowb + t;
        float v = acc[i][j][t];
        size_t lidx = (size_t)row * N + col;
        if (res) v += res[lidx];
        if (OUTMODE == 0)      ((float*)Out)[lidx] = v;
        else if (OUTMODE == 2) ((u16*)Out)[lidx] = f2bf(v);
        else if (OUTMODE == 3) {
          int orow, cofx;
          if (row < 4096) { orow = row; cofx = 0; }
          else {
            int rr = row - 4096; int bb = rr >> 11, ss = rr & 2047;
            orow = bb * S_LEN + (S_LEN - 1 - ss); cofx = 256;
          }
          ((u16*)Out)[(size_t)orow * 512 + col + cofx] = f2bf(v);
        } else {
          if (isbf) ((u16*)Out)[lidx] = f2bf(v); else ((float*)Out)[lidx] = v;
        }
      }
    }
  }
}

// ---------------- causal depthwise conv K=4 + bias + SiLU, batched ----------------
__global__ __launch_bounds__(256) void conv_kernel(
    const u16* __restrict__ xzb, const void* __restrict__ cw, const void* __restrict__ cb,
    int it, const int* __restrict__ pf, u16* __restrict__ xcb)
{
  const int isbf = *pf;
  int idx = blockIdx.x * 256 + threadIdx.x;  // 8192*512
  int r = idx >> 9, d = idx & 511;
  int chain = r >> 12, rr = r & 4095;
  int i = chain * 2 + it;
  size_t ow = (size_t)i * 2048, ob = (size_t)i * 512;
  int s = rr & 2047;
  float acc = ldw(cb, ob + d, isbf);
#pragma unroll
  for (int k = 0; k < 4; ++k) {
    int t = s - 3 + k;
    if (t >= 0)
      acc += ldw(cw, ow + (size_t)d * 4 + k, isbf) * bf2f(xzb[((size_t)(r + t - s) << 10) + d]);
  }
  xcb[idx] = f2bf(siluf(acc));
}

// ---------------- 3-phase scan: 4 n-states per thread, many blocks ----------------
// Block = 64 d x 4 ng threads. Grid (8 dblk, NCHUNK, 4 seqs).
// seq: chain = seq>>1, b = seq&1; row0 = chain*4096 + b*2048 + c*32.
__global__ __launch_bounds__(256) void scan_p1_kernel(
    const u16* __restrict__ xcb, const float* __restrict__ dBC,
    const void* __restrict__ A_log, const void* __restrict__ dtpw,
    const void* __restrict__ dtpb, int it, const int* __restrict__ pf,
    float* __restrict__ aggA, float* __restrict__ aggB)
{
  const int isbf = *pf;
  __shared__ float sall[32][64];   // dBC rows: [0:32) dt, [32:48) B, [48:64) C
  __shared__ float sd[32][64];     // delta
  __shared__ u16 sxu[32][64];      // xc bf16
  int tid = threadIdx.x;
  int di = tid >> 2, ng = tid & 3;
  int d0 = blockIdx.x << 6;
  int c = blockIdx.y, seq = blockIdx.z;
  int chain = seq >> 1, bb = seq & 1;
  int row0 = chain * 4096 + bb * S_LEN + c * CLEN;
  int i = chain * 2 + it;
  size_t oA = (size_t)i * 8192, owt = (size_t)i * 16384, obt = (size_t)i * 512;
  {
    int t = tid >> 3, e0 = (tid & 7) * 8;
    const float* p = dBC + (size_t)(row0 + t) * 64 + e0;
    *(f32x4*)&sall[t][e0]     = *(const f32x4*)p;
    *(f32x4*)&sall[t][e0 + 4] = *(const f32x4*)(p + 4);
    *(u16x8*)&sxu[t][e0] = *(const u16x8*)(xcb + (size_t)(row0 + t) * 512 + d0 + e0);
  }
  int dcol = tid & 63;
  float w_[32];
#pragma unroll
  for (int j = 0; j < 32; ++j) w_[j] = ldw(dtpw, owt + (size_t)j * 512 + d0 + dcol, isbf);
  float bias = ldw(dtpb, obt + d0 + dcol, isbf);
  __syncthreads();
#pragma unroll
  for (int k = 0; k < 8; ++k) {
    int t = (tid >> 6) + k * 4;
    float a = bias;
#pragma unroll
    for (int j4 = 0; j4 < 8; ++j4) {
      f32x4 v = *(const f32x4*)&sall[t][j4 * 4];
      a += v[0] * w_[j4 * 4] + v[1] * w_[j4 * 4 + 1] + v[2] * w_[j4 * 4 + 2] + v[3] * w_[j4 * 4 + 3];
    }
    sd[t][dcol] = softplusf(a);
  }
  __syncthreads();
  float Ac[4];
#pragma unroll
  for (int j = 0; j < 4; ++j)
    Ac[j] = -__expf(ldw(A_log, oA + (size_t)(d0 + di) * 16 + ng * 4 + j, isbf));
  float h[4] = {0.f, 0.f, 0.f, 0.f};
  float ap[4] = {1.f, 1.f, 1.f, 1.f};
#pragma unroll 8
  for (int t = 0; t < CLEN; ++t) {
    float de = sd[t][di];
    float dx = de * bf2f(sxu[t][di]);
    f32x4 B = *(const f32x4*)&sall[t][32 + ng * 4];
#pragma unroll
    for (int j = 0; j < 4; ++j) {
      float e = __expf(de * Ac[j]);
      h[j] = e * h[j] + dx * B[j];
      ap[j] *= e;
    }
  }
  size_t o = (((size_t)(seq * NCHUNK + c) * DINNER) + d0 + di) * 16 + ng * 4;
  *(f32x4*)(aggA + o) = (f32x4){ap[0], ap[1], ap[2], ap[3]};
  *(f32x4*)(aggB + o) = (f32x4){h[0], h[1], h[2], h[3]};
}

// Phase 2: exclusive prefix over chunks in place (aggB -> hpref). 128 blocks.
__global__ __launch_bounds__(256) void scan_prefix_kernel(
    const float* __restrict__ aggA, float* __restrict__ aggB)
{
  int idx = blockIdx.x * 256 + threadIdx.x;   // 4*512*16
  int n = idx & 15, d = (idx >> 4) & 511, seq = idx >> 13;
  float h = 0.f;
  for (int c = 0; c < NCHUNK; ++c) {
    size_t o = (((size_t)(seq * NCHUNK + c) * DINNER) + d) * 16 + n;
    float a = aggA[o], t = aggB[o];
    aggB[o] = h;
    h = a * h + t;
  }
}

// Phase 3: replay with true init; 2-shfl C-contraction; gated bf16 out.
__global__ __launch_bounds__(256) void scan_p3_kernel(
    const u16* __restrict__ xcb, const float* __restrict__ dBC,
    const u16* __restrict__ xzb, const float* __restrict__ hpref,
    const void* __restrict__ A_log, const void* __restrict__ Dp,
    const void* __restrict__ dtpw, const void* __restrict__ dtpb,
    int it, const int* __restrict__ pf, u16* __restrict__ ymb)
{
  const int isbf = *pf;
  __shared__ float sall[32][64];
  __shared__ float sd[32][64];
  __shared__ float sy[32][64];
  __shared__ u16 sxu[32][64];
  __shared__ u16 szu[32][64];
  int tid = threadIdx.x;
  int di = tid >> 2, ng = tid & 3;
  int d0 = blockIdx.x << 6;
  int c = blockIdx.y, seq = blockIdx.z;
  int chain = seq >> 1, bb = seq & 1;
  int row0 = chain * 4096 + bb * S_LEN + c * CLEN;
  int i = chain * 2 + it;
  size_t oA = (size_t)i * 8192, owt = (size_t)i * 16384, obt = (size_t)i * 512;
  size_t oD = (size_t)i * 512;
  {
    int t = tid >> 3, e0 = (tid & 7) * 8;
    const float* p = dBC + (size_t)(row0 + t) * 64 + e0;
    *(f32x4*)&sall[t][e0]     = *(const f32x4*)p;
    *(f32x4*)&sall[t][e0 + 4] = *(const f32x4*)(p + 4);
    *(u16x8*)&sxu[t][e0] = *(const u16x8*)(xcb + (size_t)(row0 + t) * 512 + d0 + e0);
    *(u16x8*)&szu[t][e0] = *(const u16x8*)(xzb + ((size_t)(row0 + t) << 10) + 512 + d0 + e0);
  }
  int dcol = tid & 63;
  float w_[32];
#pragma unroll
  for (int j = 0; j < 32; ++j) w_[j] = ldw(dtpw, owt + (size_t)j * 512 + d0 + dcol, isbf);
  float bias = ldw(dtpb, obt + d0 + dcol, isbf);
  __syncthreads();
#pragma unroll
  for (int k = 0; k < 8; ++k) {
    int t = (tid >> 6) + k * 4;
    float a = bias;
#pragma unroll
    for (int j4 = 0; j4 < 8; ++j4) {
      f32x4 v = *(const f32x4*)&sall[t][j4 * 4];
      a += v[0] * w_[j4 * 4] + v[1] * w_[j4 * 4 + 1] + v[2] * w_[j4 * 4 + 2] + v[3] * w_[j4 * 4 + 3];
    }
    sd[t][dcol] = softplusf(a);
  }
  __syncthreads();
  float Ac[4];
#pragma unroll
  for (int j = 0; j < 4; ++j)
    Ac[j] = -__expf(ldw(A_log, oA + (size_t)(d0 + di) * 16 + ng * 4 + j, isbf));
  float Dv = ldw(Dp, oD + d0 + di, isbf);
  float h[4];
  size_t o = (((size_t)(seq * NCHUNK + c) * DINNER) + d0 + di) * 16 + ng * 4;
  {
    f32x4 v = *(const f32x4*)(hpref + o);
    h[0] = v[0]; h[1] = v[1]; h[2] = v[2]; h[3] = v[3];
  }
#pragma unroll 8
  for (int t = 0; t < CLEN; ++t) {
    float de = sd[t][di];
    float xv = bf2f(sxu[t][di]);
    float dx = de * xv;
    f32x4 B = *(const f32x4*)&sall[t][32 + ng * 4];
    f32x4 C = *(const f32x4*)&sall[t][48 + ng * 4];
    float yc = 0.f;
#pragma unroll
    for (int j = 0; j < 4; ++j) {
      float e = __expf(de * Ac[j]);
      h[j] = e * h[j] + dx * B[j];
      yc += h[j] * C[j];
    }
    yc += __shfl_xor(yc, 1, 64);
    yc += __shfl_xor(yc, 2, 64);
    if (ng == 0) sy[t][di] = yc + Dv * xv;
  }
  __syncthreads();
#pragma unroll
  for (int k = 0; k < 8; ++k) {
    int t = (tid >> 6) + k * 4;
    float y = sy[t][dcol];
    float z = bf2f(szu[t][dcol]);
    ymb[(size_t)(row0 + t) * 512 + d0 + dcol] = f2bf(y * siluf(z));
  }
}

extern "C" void kernel_launch(void* const* d_in, const int* in_sizes, int n_in,
                              void* d_out, int out_size, void* d_ws, size_t ws_size,
                              hipStream_t stream)
{
  const void* x       = d_in[0];
  const void* in_w    = d_in[1];
  const void* conv_w  = d_in[2];
  const void* conv_b  = d_in[3];
  const void* A_log   = d_in[4];
  const void* xd_w    = d_in[5];
  const void* xB_w    = d_in[6];
  const void* xC_w    = d_in[7];
  const void* dtp_w   = d_in[8];
  const void* dtp_b   = d_in[9];
  const void* Dp      = d_in[10];
  const void* out_w   = d_in[11];
  const void* ln_g    = d_in[12];
  const void* ln_b    = d_in[13];
  const void* merge_w = d_in[14];

  // ---- workspace (~61.5 MB; proven-safe >= 65.5 MB) ----
  float* ws    = (float*)d_ws;
  float* res   = ws;                             // 8192x256 f32 (2M fl)
  float* dBC   = res + (size_t)8192 * 256;       // 8192x64 (0.5M fl)
  float* aggA  = dBC + (size_t)8192 * 64;        // 4*64*512*16 (2M fl) [ym alias]
  float* aggB  = aggA + (size_t)2097152;         // 2M fl (-> hpref)
  u16*   xz_bf = (u16*)(aggB + (size_t)2097152); // 8192x1024 u16 [obA aliases head]
  u16*   xn_bf = xz_bf + (size_t)8192 * 1024;    // 8192x256 u16
  u16*   xc_bf = xn_bf + (size_t)8192 * 256;     // 8192x512 u16
  u16*   cat_bf= xc_bf + (size_t)8192 * 512;     // 4096x512 u16
  u16*   Wp_in = cat_bf + (size_t)4096 * 512;    // 4*256*1024
  u16*   Wp_out= Wp_in + (size_t)4 * 262144;     // 4*512*256
  u16*   Wp_mg = Wp_out + (size_t)4 * 131072;    // 512*256
  u16*   Wp_all= Wp_mg + (size_t)131072;         // 4*512*64
  int*   flagp = (int*)(Wp_all + (size_t)4 * 32768);
  u16*   obA_bf= xz_bf;          // alias: obA consumed before iter1 in-proj rewrites xz
  u16*   ym_bf = (u16*)aggA;     // alias: aggA dead after prefix

  dim3 blk(256);
  hipLaunchKernelGGL(detect_kernel, dim3(1), blk, 0, stream, x, flagp);
  hipLaunchKernelGGL(wpack_kernel, dim3(16, 8, 4), blk, 0, stream, in_w, flagp, Wp_in, 256, 1024);
  hipLaunchKernelGGL(wpack_kernel, dim3(4, 16, 4), blk, 0, stream, out_w, flagp, Wp_out, 512, 256);
  hipLaunchKernelGGL(wpack_kernel, dim3(4, 16, 1), blk, 0, stream, merge_w, flagp, Wp_mg, 512, 256);
  hipLaunchKernelGGL(wpack_fused_kernel, dim3(1, 16, 4), blk, 0, stream,
      xd_w, xB_w, xC_w, flagp, Wp_all);

  for (int it = 0; it < 2; ++it) {
    hipLaunchKernelGGL(ln_kernel, dim3(8192), blk, 0, stream,
        x, obA_bf, it, ln_g, ln_b, flagp, res, xn_bf);
    hipLaunchKernelGGL((mfma_gemm<128, 2>), dim3(8, 64), blk, 0, stream,
        xn_bf, Wp_in, (size_t)it * 262144, (size_t)(2 + it) * 262144, 4096,
        (const float*)nullptr, (void*)xz_bf, flagp, 1024, 256);
    hipLaunchKernelGGL(conv_kernel, dim3(16384), blk, 0, stream,
        xz_bf, conv_w, conv_b, it, flagp, xc_bf);
    hipLaunchKernelGGL((mfma_gemm<64, 0>), dim3(1, 64), blk, 0, stream,
        xc_bf, Wp_all, (size_t)it * 32768, (size_t)(2 + it) * 32768, 4096,
        (const float*)nullptr, (void*)dBC, flagp, 64, 512);
    hipLaunchKernelGGL(scan_p1_kernel, dim3(8, NCHUNK, 4), blk, 0, stream,
        xc_bf, dBC, A_log, dtp_w, dtp_b, it, flagp, aggA, aggB);
    hipLaunchKernelGGL(scan_prefix_kernel, dim3(128), blk, 0, stream, aggA, aggB);
    hipLaunchKernelGGL(scan_p3_kernel, dim3(8, NCHUNK, 4), blk, 0, stream,
        xc_bf, dBC, xz_bf, aggB, A_log, Dp, dtp_w, dtp_b, it, flagp, ym_bf);
    if (it == 0) {
      hipLaunchKernelGGL((mfma_gemm<128, 2>), dim3(2, 64), blk, 0, stream,
          ym_bf, Wp_out, (size_t)0, (size_t)2 * 131072, 4096,
          res, (void*)obA_bf, flagp, 256, 512);
    } else {
      hipLaunchKernelGGL((mfma_gemm<128, 3>), dim3(2, 64), blk, 0, stream,
          ym_bf, Wp_out, (size_t)1 * 131072, (size_t)3 * 131072, 4096,
          res, (void*)cat_bf, flagp, 256, 512);
    }
  }
  hipLaunchKernelGGL((mfma_gemm<128, 1>), dim3(2, 32), blk, 0, stream,
      cat_bf, Wp_mg, (size_t)0, (size_t)0, 0,
      (const float*)nullptr, d_out, flagp, 256, 512);
}